// Round 13
// baseline (356.776 us; speedup 1.0000x reference)
//
#include <hip/hip_runtime.h>
#include <stdint.h>

#define D 256

typedef __attribute__((ext_vector_type(8))) short bf16x8;
typedef __attribute__((ext_vector_type(4))) float f32x4;

__device__ inline unsigned short f2bf(float f) {
    union { float f; uint32_t u; } v; v.f = f;
    return (unsigned short)((v.u + 0x7FFFu + ((v.u >> 16) & 1u)) >> 16);
}
__device__ inline float bf2f(unsigned short b) {
    return __uint_as_float(((uint32_t)b) << 16);
}

// segment geometry (padded to 1024-multiples for the block scan)
#define SEG0 0
#define SEG1 50176
#define SEG2 62464
#define CURTOT 66560          // 50176+12288+4096
#define NBLK 65               // seg0 blocks 0-48, seg1 49-60, seg2 61-64

#define WBLK 1536             // 6*65536/256

// ---------- fused preprocessing: weights -> bf16 [col][k] + edge count -------
struct PreArgs {
    const float* w[6];
    unsigned short* wt;
    const int* d0; const int* d1; const int* d2;
    int* cur;
    int E0, E01, Etot;
};

__global__ __launch_bounds__(256) void fused_pre(PreArgs a)
{
    int b = blockIdx.x;
    if (b < WBLK) {
        int t = b * 256 + threadIdx.x;
        int m = t >> 16, e = t & 65535;
        int col = e >> 8, k = e & 255;
        a.wt[t] = f2bf(a.w[m][(k << 8) + col]);
    } else {
        int e = (b - WBLK) * 256 + threadIdx.x;
        if (e >= a.Etot) return;
        int base, d;
        if (e < a.E0)       { base = SEG0; d = a.d0[e]; }
        else if (e < a.E01) { base = SEG1; d = a.d1[e - a.E0]; }
        else                { base = SEG2; d = a.d2[e - a.E01]; }
        atomicAdd(&a.cur[base + d], 1);
    }
}

// ---------- single-pass segmented scan with decoupled lookback ---------------
__global__ __launch_bounds__(256) void scan_lookback(
    int* __restrict__ cur, unsigned int* __restrict__ flag)
{
    __shared__ int wsum[4];
    __shared__ int sprefix;
    int tid = threadIdx.x, lane = tid & 63, wid = tid >> 6;
    int b = blockIdx.x;
    int base = b * 1024 + tid * 4;
    int4 v = *(int4*)(cur + base);
    int t0 = v.x, t01 = t0 + v.y, t012 = t01 + v.z, tot = t012 + v.w;
    int incl = tot;
    #pragma unroll
    for (int ofs = 1; ofs < 64; ofs <<= 1) {
        int t = __shfl_up(incl, ofs, 64);
        if (lane >= ofs) incl += t;
    }
    if (lane == 63) wsum[wid] = incl;
    __syncthreads();
    if (tid == 0) {
        int run = 0;
        #pragma unroll
        for (int w = 0; w < 4; ++w) { int t = wsum[w]; wsum[w] = run; run += t; }
        int segfirst = (b >= 61) ? 61 : (b >= 49) ? 49 : 0;
        int pfx = 0;
        if (b != segfirst) {
            unsigned int f;
            do {
                f = __hip_atomic_load(&flag[b - 1], __ATOMIC_ACQUIRE,
                                      __HIP_MEMORY_SCOPE_AGENT);
            } while (f == 0);
            pfx = (int)(f - 1u);
        }
        __hip_atomic_store(&flag[b], (unsigned int)(pfx + run) + 1u,
                           __ATOMIC_RELEASE, __HIP_MEMORY_SCOPE_AGENT);
        sprefix = pfx;
    }
    __syncthreads();
    int add = sprefix + wsum[wid] + incl - tot;
    v.x = add; v.y = add + t0; v.z = add + t01; v.w = add + t012;
    *(int4*)(cur + base) = v;
}

// fill: idx[cursor(dst)] = src; afterwards cur[] holds INCLUSIVE offsets
__global__ __launch_bounds__(256) void fill_all(
    const int* __restrict__ s0, const int* __restrict__ s1, const int* __restrict__ s2,
    const int* __restrict__ d0, const int* __restrict__ d1, const int* __restrict__ d2,
    int* __restrict__ cur, int* __restrict__ idx, int E0, int E01, int Etot)
{
    int e = blockIdx.x * 256 + threadIdx.x;
    if (e >= Etot) return;
    int base, d, s, ib;
    if (e < E0)       { base = SEG0; d = d0[e];       s = s0[e];       ib = 0; }
    else if (e < E01) { base = SEG1; d = d1[e - E0];  s = s1[e - E0];  ib = E0; }
    else              { base = SEG2; d = d2[e - E01]; s = s2[e - E01]; ib = E01; }
    int p = atomicAdd(&cur[base + d], 1);
    idx[ib + p] = s;
}

// ---------- gather + mean (one wave per dst row), 4-deep unroll --------------
template<int BF16IN>
__global__ __launch_bounds__(256) void gather_mean_k(
    const void* __restrict__ hv, const int* __restrict__ idx,
    const int* __restrict__ curseg, unsigned short* __restrict__ mean, int M)
{
    int t = blockIdx.x * blockDim.x + threadIdx.x;
    int w = t >> 6, lane = t & 63;
    if (w >= M) return;
    int e0 = w ? curseg[w - 1] : 0;
    int e1 = curseg[w];
    float4 acc0 = make_float4(0.f, 0.f, 0.f, 0.f);
    float4 acc1 = make_float4(0.f, 0.f, 0.f, 0.f);
    int e = e0;
    if (BF16IN) {
        const unsigned short* h = (const unsigned short*)hv;
        for (; e + 3 < e1; e += 4) {
            int sa = idx[e], sb = idx[e + 1], sc = idx[e + 2], sd = idx[e + 3];
            ushort4 va = *(const ushort4*)(h + (size_t)sa * D + lane * 4);
            ushort4 vb = *(const ushort4*)(h + (size_t)sb * D + lane * 4);
            ushort4 vc = *(const ushort4*)(h + (size_t)sc * D + lane * 4);
            ushort4 vd = *(const ushort4*)(h + (size_t)sd * D + lane * 4);
            acc0.x += bf2f(va.x) + bf2f(vb.x);
            acc0.y += bf2f(va.y) + bf2f(vb.y);
            acc0.z += bf2f(va.z) + bf2f(vb.z);
            acc0.w += bf2f(va.w) + bf2f(vb.w);
            acc1.x += bf2f(vc.x) + bf2f(vd.x);
            acc1.y += bf2f(vc.y) + bf2f(vd.y);
            acc1.z += bf2f(vc.z) + bf2f(vd.z);
            acc1.w += bf2f(vc.w) + bf2f(vd.w);
        }
        for (; e < e1; ++e) {
            int sa = idx[e];
            ushort4 va = *(const ushort4*)(h + (size_t)sa * D + lane * 4);
            acc0.x += bf2f(va.x); acc0.y += bf2f(va.y);
            acc0.z += bf2f(va.z); acc0.w += bf2f(va.w);
        }
    } else {
        const float* h = (const float*)hv;
        for (; e + 3 < e1; e += 4) {
            int sa = idx[e], sb = idx[e + 1], sc = idx[e + 2], sd = idx[e + 3];
            float4 va = *((const float4*)(h + (size_t)sa * D) + lane);
            float4 vb = *((const float4*)(h + (size_t)sb * D) + lane);
            float4 vc = *((const float4*)(h + (size_t)sc * D) + lane);
            float4 vd = *((const float4*)(h + (size_t)sd * D) + lane);
            acc0.x += va.x + vb.x; acc0.y += va.y + vb.y;
            acc0.z += va.z + vb.z; acc0.w += va.w + vb.w;
            acc1.x += vc.x + vd.x; acc1.y += vc.y + vd.y;
            acc1.z += vc.z + vd.z; acc1.w += vc.w + vd.w;
        }
        for (; e < e1; ++e) {
            int sa = idx[e];
            float4 va = *((const float4*)(h + (size_t)sa * D) + lane);
            acc0.x += va.x; acc0.y += va.y; acc0.z += va.z; acc0.w += va.w;
        }
    }
    acc0.x += acc1.x; acc0.y += acc1.y; acc0.z += acc1.z; acc0.w += acc1.w;
    float r = 1.0f / fmaxf((float)(e1 - e0), 1.0f);
    ushort4 o;
    o.x = f2bf(acc0.x * r); o.y = f2bf(acc0.y * r);
    o.z = f2bf(acc0.z * r); o.w = f2bf(acc0.w * r);
    *(ushort4*)(mean + (size_t)w * D + lane * 4) = o;
}

// ---------- DIRECT MFMA GEMM (no LDS, no barriers) ----------
// out = relu(A1@W1 + A2@W2 + b). 128x128 block tile, 4 waves (2x2) of 64x64.
// All operands are L2/L3-resident (B = 256KB weights shared by all blocks;
// A rows L3-hot from the gather) -> fragments load straight to registers.
// Per-instruction access = 16 rows x 16B at 512B stride -> 16 full 64B lines.
template<int FINAL, int A1F32>
__global__ __launch_bounds__(256) void sage_gemm_direct(
    const void* __restrict__ A1v,
    const unsigned short* __restrict__ A2,
    const unsigned short* __restrict__ Wt1,   // [col][k] bf16
    const unsigned short* __restrict__ Wt2,   // [col][k] bf16
    const float* __restrict__ bias,
    void* __restrict__ outv,
    int M)
{
    int tid = threadIdx.x;
    int lane = tid & 63, wid = tid >> 6;
    int wr = wid >> 1, wc = wid & 1;
    int m0 = blockIdx.x * 128, n0 = blockIdx.y * 128;
    int l15 = lane & 15, lq = lane >> 4;

    // per-fragment row/col bases (row clamped for the M-tail)
    size_t aro[4], bco[4];
    int arow_i[4];
    #pragma unroll
    for (int i = 0; i < 4; ++i) {
        int r = m0 + wr * 64 + i * 16 + l15;
        if (r >= M) r = M - 1;
        arow_i[i] = r;
        aro[i] = (size_t)r * 256;
        bco[i] = (size_t)(n0 + wc * 64 + i * 16 + l15) * 256;
    }

    f32x4 acc[4][4] = {};

    #pragma unroll 2
    for (int kt = 0; kt < 16; ++kt) {
        int kk = (kt & 7) * 32 + lq * 8;
        bf16x8 af[4], bfr[4];
        if (A1F32 && kt < 8) {
            const float* A = (const float*)A1v;
            #pragma unroll
            for (int i = 0; i < 4; ++i) {
                const float* p = A + aro[i] + kk;
                float4 u0 = *(const float4*)p;
                float4 u1 = *(const float4*)(p + 4);
                unsigned short rr[8] = {f2bf(u0.x), f2bf(u0.y), f2bf(u0.z), f2bf(u0.w),
                                        f2bf(u1.x), f2bf(u1.y), f2bf(u1.z), f2bf(u1.w)};
                af[i] = *(const bf16x8*)rr;
            }
        } else {
            const unsigned short* A = (kt < 8) ? (const unsigned short*)A1v : A2;
            #pragma unroll
            for (int i = 0; i < 4; ++i)
                af[i] = *(const bf16x8*)(A + aro[i] + kk);
        }
        {
            const unsigned short* B = (kt < 8) ? Wt1 : Wt2;
            #pragma unroll
            for (int i = 0; i < 4; ++i)
                bfr[i] = *(const bf16x8*)(B + bco[i] + kk);
        }
        #pragma unroll
        for (int mr = 0; mr < 4; ++mr)
            #pragma unroll
            for (int nc = 0; nc < 4; ++nc)
                acc[mr][nc] = __builtin_amdgcn_mfma_f32_16x16x32_bf16(
                    af[mr], bfr[nc], acc[mr][nc], 0, 0, 0);
    }

    // epilogue: bias + relu; C/D layout col=lane&15, row=(lane>>4)*4+reg
    #pragma unroll
    for (int nc = 0; nc < 4; ++nc) {
        int gc = n0 + wc * 64 + nc * 16 + l15;
        float bv = bias[gc];
        #pragma unroll
        for (int mr = 0; mr < 4; ++mr) {
            #pragma unroll
            for (int reg = 0; reg < 4; ++reg) {
                int gr = m0 + wr * 64 + mr * 16 + lq * 4 + reg;
                if (gr < M) {
                    float v = fmaxf(acc[mr][nc][reg] + bv, 0.f);
                    if (FINAL) ((float*)outv)[(size_t)gr * 256 + gc] = v;
                    else ((unsigned short*)outv)[(size_t)gr * 256 + gc] = f2bf(v);
                }
            }
        }
    }
}

extern "C" void kernel_launch(void* const* d_in, const int* in_sizes, int n_in,
                              void* d_out, int out_size, void* d_ws, size_t ws_size,
                              hipStream_t stream) {
    const float* x = (const float*)d_in[0];
    const float* Wself[3]  = {(const float*)d_in[1], (const float*)d_in[4], (const float*)d_in[7]};
    const float* Wneigh[3] = {(const float*)d_in[2], (const float*)d_in[5], (const float*)d_in[8]};
    const float* bias[3]   = {(const float*)d_in[3], (const float*)d_in[6], (const float*)d_in[9]};
    const int* src[3] = {(const int*)d_in[10], (const int*)d_in[12], (const int*)d_in[14]};
    const int* dst[3] = {(const int*)d_in[11], (const int*)d_in[13], (const int*)d_in[15]};
    int E[3]    = {in_sizes[10], in_sizes[12], in_sizes[14]};
    int E0 = E[0], E01 = E[0] + E[1], Etot = E[0] + E[1] + E[2];

    // workspace
    unsigned short* h1b = (unsigned short*)d_ws;            // 50000*256
    unsigned short* h2b = h1b + (size_t)50000 * D;          // 12000*256
    unsigned short* meanb = h2b + (size_t)12000 * D;        // 50000*256
    unsigned short* wt  = meanb + (size_t)50000 * D;        // 6*65536 [col][k]
    int* cur            = (int*)(wt + 6 * 65536);           // CURTOT
    unsigned int* flag  = (unsigned int*)(cur + CURTOT);    // NBLK (pad 80)
    int* idxa           = (int*)(flag + 80);                // Etot (<=660000)

    hipMemsetAsync(cur, 0, (CURTOT + 80) * sizeof(int), stream);

    PreArgs pa;
    pa.w[0] = Wself[0]; pa.w[1] = Wneigh[0];
    pa.w[2] = Wself[1]; pa.w[3] = Wneigh[1];
    pa.w[4] = Wself[2]; pa.w[5] = Wneigh[2];
    pa.wt = wt;
    pa.d0 = dst[0]; pa.d1 = dst[1]; pa.d2 = dst[2];
    pa.cur = cur; pa.E0 = E0; pa.E01 = E01; pa.Etot = Etot;
    int cblk = (Etot + 255) / 256;
    fused_pre<<<WBLK + cblk, 256, 0, stream>>>(pa);

    scan_lookback<<<NBLK, 256, 0, stream>>>(cur, flag);

    fill_all<<<(Etot + 255) / 256, 256, 0, stream>>>(src[0], src[1], src[2],
        dst[0], dst[1], dst[2], cur, idxa, E0, E01, Etot);

    // layer 0
    gather_mean_k<0><<<(50000 * 64 + 255) / 256, 256, 0, stream>>>(
        x, idxa + 0, cur + SEG0, meanb, 50000);
    sage_gemm_direct<0, 1><<<dim3((50000 + 127) / 128, 2), 256, 0, stream>>>(
        x, meanb, wt + 0 * 65536, wt + 1 * 65536, bias[0], h1b, 50000);

    // layer 1
    gather_mean_k<1><<<(12000 * 64 + 255) / 256, 256, 0, stream>>>(
        h1b, idxa + E0, cur + SEG1, meanb, 12000);
    sage_gemm_direct<0, 0><<<dim3((12000 + 127) / 128, 2), 256, 0, stream>>>(
        h1b, meanb, wt + 2 * 65536, wt + 3 * 65536, bias[1], h2b, 12000);

    // layer 2
    gather_mean_k<1><<<(4000 * 64 + 255) / 256, 256, 0, stream>>>(
        h2b, idxa + E01, cur + SEG2, meanb, 4000);
    sage_gemm_direct<1, 0><<<dim3((4000 + 127) / 128, 2), 256, 0, stream>>>(
        h2b, meanb, wt + 4 * 65536, wt + 5 * 65536, bias[2], d_out, 4000);
}

// Round 14
// 303.841 us; speedup vs baseline: 1.1742x; 1.1742x over previous
//
#include <hip/hip_runtime.h>
#include <stdint.h>

#define D 256

typedef __attribute__((ext_vector_type(8))) short bf16x8;
typedef __attribute__((ext_vector_type(4))) float f32x4;

__device__ inline unsigned short f2bf(float f) {
    union { float f; uint32_t u; } v; v.f = f;
    return (unsigned short)((v.u + 0x7FFFu + ((v.u >> 16) & 1u)) >> 16);
}
__device__ inline float bf2f(unsigned short b) {
    return __uint_as_float(((uint32_t)b) << 16);
}

// segment geometry (padded to 1024-multiples for the block scan)
#define SEG0 0
#define SEG1 50176
#define SEG2 62464
#define CURTOT 66560          // 50176+12288+4096
#define NBLK 65               // seg0 blocks 0-48, seg1 49-60, seg2 61-64

// ---------- weight transpose: LDS-tiled, coalesced both sides ---------------
// 6 matrices of 256x256; 16 tiles of 64x64 each -> 96 blocks of 256 threads.
// out: wt[m][col*256 + k] bf16 (col-major for GEMM B staging).
struct WtArgs { const float* w[6]; unsigned short* wt; };
__global__ __launch_bounds__(256) void transpose_w(WtArgs a)
{
    __shared__ float tile[64][65];
    int b = blockIdx.x;
    int m = b >> 4;              // matrix
    int t = b & 15;
    int r0 = (t >> 2) * 64, c0 = (t & 3) * 64;
    int ty = threadIdx.x >> 4, tx = threadIdx.x & 15;
    const float* w = a.w[m];
    #pragma unroll
    for (int i = 0; i < 4; ++i) {
        int row = ty * 4 + i;
        float4 v = *(const float4*)(w + (size_t)(r0 + row) * 256 + c0 + tx * 4);
        tile[row][tx * 4 + 0] = v.x;
        tile[row][tx * 4 + 1] = v.y;
        tile[row][tx * 4 + 2] = v.z;
        tile[row][tx * 4 + 3] = v.w;
    }
    __syncthreads();
    unsigned short* o = a.wt + (size_t)m * 65536;
    #pragma unroll
    for (int i = 0; i < 4; ++i) {
        int col = ty * 4 + i;    // output row = source col
        ushort4 u;
        u.x = f2bf(tile[tx * 4 + 0][col]);
        u.y = f2bf(tile[tx * 4 + 1][col]);
        u.z = f2bf(tile[tx * 4 + 2][col]);
        u.w = f2bf(tile[tx * 4 + 3][col]);
        *(ushort4*)(o + (size_t)(c0 + col) * 256 + r0 + tx * 4) = u;
    }
}

// ---------- edge count ----------
__global__ __launch_bounds__(256) void count_all(
    const int* __restrict__ d0, const int* __restrict__ d1, const int* __restrict__ d2,
    int* __restrict__ cur, int E0, int E01, int Etot)
{
    int e = blockIdx.x * 256 + threadIdx.x;
    if (e >= Etot) return;
    int base, d;
    if (e < E0)       { base = SEG0; d = d0[e]; }
    else if (e < E01) { base = SEG1; d = d1[e - E0]; }
    else              { base = SEG2; d = d2[e - E01]; }
    atomicAdd(&cur[base + d], 1);
}

// ---------- single-pass segmented scan with decoupled lookback ---------------
__global__ __launch_bounds__(256) void scan_lookback(
    int* __restrict__ cur, unsigned int* __restrict__ flag)
{
    __shared__ int wsum[4];
    __shared__ int sprefix;
    int tid = threadIdx.x, lane = tid & 63, wid = tid >> 6;
    int b = blockIdx.x;
    int base = b * 1024 + tid * 4;
    int4 v = *(int4*)(cur + base);
    int t0 = v.x, t01 = t0 + v.y, t012 = t01 + v.z, tot = t012 + v.w;
    int incl = tot;
    #pragma unroll
    for (int ofs = 1; ofs < 64; ofs <<= 1) {
        int t = __shfl_up(incl, ofs, 64);
        if (lane >= ofs) incl += t;
    }
    if (lane == 63) wsum[wid] = incl;
    __syncthreads();
    if (tid == 0) {
        int run = 0;
        #pragma unroll
        for (int w = 0; w < 4; ++w) { int t = wsum[w]; wsum[w] = run; run += t; }
        int segfirst = (b >= 61) ? 61 : (b >= 49) ? 49 : 0;
        int pfx = 0;
        if (b != segfirst) {
            unsigned int f;
            do {
                f = __hip_atomic_load(&flag[b - 1], __ATOMIC_ACQUIRE,
                                      __HIP_MEMORY_SCOPE_AGENT);
            } while (f == 0);
            pfx = (int)(f - 1u);
        }
        __hip_atomic_store(&flag[b], (unsigned int)(pfx + run) + 1u,
                           __ATOMIC_RELEASE, __HIP_MEMORY_SCOPE_AGENT);
        sprefix = pfx;
    }
    __syncthreads();
    int add = sprefix + wsum[wid] + incl - tot;
    v.x = add; v.y = add + t0; v.z = add + t01; v.w = add + t012;
    *(int4*)(cur + base) = v;
}

// fill: idx[cursor(dst)] = src; afterwards cur[] holds INCLUSIVE offsets
__global__ __launch_bounds__(256) void fill_all(
    const int* __restrict__ s0, const int* __restrict__ s1, const int* __restrict__ s2,
    const int* __restrict__ d0, const int* __restrict__ d1, const int* __restrict__ d2,
    int* __restrict__ cur, int* __restrict__ idx, int E0, int E01, int Etot)
{
    int e = blockIdx.x * 256 + threadIdx.x;
    if (e >= Etot) return;
    int base, d, s, ib;
    if (e < E0)       { base = SEG0; d = d0[e];       s = s0[e];       ib = 0; }
    else if (e < E01) { base = SEG1; d = d1[e - E0];  s = s1[e - E0];  ib = E0; }
    else              { base = SEG2; d = d2[e - E01]; s = s2[e - E01]; ib = E01; }
    int p = atomicAdd(&cur[base + d], 1);
    idx[ib + p] = s;
}

// ---------- gather + mean (one wave per dst row), 4-deep unroll --------------
template<int BF16IN>
__global__ __launch_bounds__(256) void gather_mean_k(
    const void* __restrict__ hv, const int* __restrict__ idx,
    const int* __restrict__ curseg, unsigned short* __restrict__ mean, int M)
{
    int t = blockIdx.x * blockDim.x + threadIdx.x;
    int w = t >> 6, lane = t & 63;
    if (w >= M) return;
    int e0 = w ? curseg[w - 1] : 0;
    int e1 = curseg[w];
    float4 acc0 = make_float4(0.f, 0.f, 0.f, 0.f);
    float4 acc1 = make_float4(0.f, 0.f, 0.f, 0.f);
    int e = e0;
    if (BF16IN) {
        const unsigned short* h = (const unsigned short*)hv;
        for (; e + 3 < e1; e += 4) {
            int sa = idx[e], sb = idx[e + 1], sc = idx[e + 2], sd = idx[e + 3];
            ushort4 va = *(const ushort4*)(h + (size_t)sa * D + lane * 4);
            ushort4 vb = *(const ushort4*)(h + (size_t)sb * D + lane * 4);
            ushort4 vc = *(const ushort4*)(h + (size_t)sc * D + lane * 4);
            ushort4 vd = *(const ushort4*)(h + (size_t)sd * D + lane * 4);
            acc0.x += bf2f(va.x) + bf2f(vb.x);
            acc0.y += bf2f(va.y) + bf2f(vb.y);
            acc0.z += bf2f(va.z) + bf2f(vb.z);
            acc0.w += bf2f(va.w) + bf2f(vb.w);
            acc1.x += bf2f(vc.x) + bf2f(vd.x);
            acc1.y += bf2f(vc.y) + bf2f(vd.y);
            acc1.z += bf2f(vc.z) + bf2f(vd.z);
            acc1.w += bf2f(vc.w) + bf2f(vd.w);
        }
        for (; e < e1; ++e) {
            int sa = idx[e];
            ushort4 va = *(const ushort4*)(h + (size_t)sa * D + lane * 4);
            acc0.x += bf2f(va.x); acc0.y += bf2f(va.y);
            acc0.z += bf2f(va.z); acc0.w += bf2f(va.w);
        }
    } else {
        const float* h = (const float*)hv;
        for (; e + 3 < e1; e += 4) {
            int sa = idx[e], sb = idx[e + 1], sc = idx[e + 2], sd = idx[e + 3];
            float4 va = *((const float4*)(h + (size_t)sa * D) + lane);
            float4 vb = *((const float4*)(h + (size_t)sb * D) + lane);
            float4 vc = *((const float4*)(h + (size_t)sc * D) + lane);
            float4 vd = *((const float4*)(h + (size_t)sd * D) + lane);
            acc0.x += va.x + vb.x; acc0.y += va.y + vb.y;
            acc0.z += va.z + vb.z; acc0.w += va.w + vb.w;
            acc1.x += vc.x + vd.x; acc1.y += vc.y + vd.y;
            acc1.z += vc.z + vd.z; acc1.w += vc.w + vd.w;
        }
        for (; e < e1; ++e) {
            int sa = idx[e];
            float4 va = *((const float4*)(h + (size_t)sa * D) + lane);
            acc0.x += va.x; acc0.y += va.y; acc0.z += va.z; acc0.w += va.w;
        }
    }
    acc0.x += acc1.x; acc0.y += acc1.y; acc0.z += acc1.z; acc0.w += acc1.w;
    float r = 1.0f / fmaxf((float)(e1 - e0), 1.0f);
    ushort4 o;
    o.x = f2bf(acc0.x * r); o.y = f2bf(acc0.y * r);
    o.z = f2bf(acc0.z * r); o.w = f2bf(acc0.w * r);
    *(ushort4*)(mean + (size_t)w * D + lane * 4) = o;
}

// ---------- MFMA GEMM, BK=64 macro-steps ----------
// out = relu(A1@W1 + A2@W2 + b). 128x128 tile, 4 waves (2x2) of 64x64.
// Each macro-step stages TWO 32-k subtiles (As[2]/Bs[2], 32KB LDS) with ONE
// barrier pair, then runs 32 MFMAs -> half the vmcnt-drain+barrier cost of
// the 16-step version (measured 78us warm @222TF).
template<int FINAL, int A1F32>
__global__ __launch_bounds__(256) void sage_gemm_db(
    const void* __restrict__ A1v,
    const unsigned short* __restrict__ A2,
    const unsigned short* __restrict__ Wt1,   // [col][k] bf16
    const unsigned short* __restrict__ Wt2,   // [col][k] bf16
    const float* __restrict__ bias,
    void* __restrict__ outv,
    int M)
{
    __shared__ unsigned short As[2][128 * 32];   // 16 KB
    __shared__ unsigned short Bs[2][128 * 32];   // 16 KB

    int tid = threadIdx.x;
    int lane = tid & 63, wid = tid >> 6;
    int wr = wid >> 1, wc = wid & 1;
    int m0 = blockIdx.x * 128, n0 = blockIdx.y * 128;
    int l15 = lane & 15, lq = lane >> 4;

    f32x4 acc[4][4] = {};

    for (int s = 0; s < 8; ++s) {
        // ---- stage two subtiles ----
        #pragma unroll
        for (int h = 0; h < 2; ++h) {
            int kt = 2 * s + h;
            int kk = (kt & 7) * 32;
            if (A1F32 && kt < 8) {
                const float* A = (const float*)A1v;
                #pragma unroll
                for (int q = 0; q < 2; ++q) {
                    int ch = q * 256 + tid;
                    int r = ch >> 2, c16 = ch & 3;
                    int gr = m0 + r; if (gr >= M) gr = M - 1;
                    const float* p = A + (size_t)gr * 256 + kk + c16 * 8;
                    float4 u0 = *(const float4*)p;
                    float4 u1 = *(const float4*)(p + 4);
                    unsigned short rr[8] = {f2bf(u0.x), f2bf(u0.y), f2bf(u0.z), f2bf(u0.w),
                                            f2bf(u1.x), f2bf(u1.y), f2bf(u1.z), f2bf(u1.w)};
                    *(uint4*)(As[h] + ch * 8) = *(uint4*)rr;
                }
            } else {
                const unsigned short* A = (kt < 8) ? (const unsigned short*)A1v : A2;
                #pragma unroll
                for (int q = 0; q < 2; ++q) {
                    int ch = q * 256 + tid;
                    int r = ch >> 2, c16 = ch & 3;
                    int gr = m0 + r; if (gr >= M) gr = M - 1;
                    const unsigned short* p = A + (size_t)gr * 256 + kk + c16 * 8;
                    __builtin_amdgcn_global_load_lds(
                        (const __attribute__((address_space(1))) void*)p,
                        (__attribute__((address_space(3))) void*)(As[h] + (q * 256 + wid * 64) * 8),
                        16, 0, 0);
                }
            }
            const unsigned short* B = (kt < 8) ? Wt1 : Wt2;
            #pragma unroll
            for (int q = 0; q < 2; ++q) {
                int ch = q * 256 + tid;
                int col = ch >> 2, c16 = ch & 3;
                const unsigned short* p = B + (size_t)(n0 + col) * 256 + kk + c16 * 8;
                __builtin_amdgcn_global_load_lds(
                    (const __attribute__((address_space(1))) void*)p,
                    (__attribute__((address_space(3))) void*)(Bs[h] + (q * 256 + wid * 64) * 8),
                    16, 0, 0);
            }
        }
        __syncthreads();

        // ---- compute both subtiles ----
        #pragma unroll
        for (int h = 0; h < 2; ++h) {
            bf16x8 af[4], bfr[4];
            #pragma unroll
            for (int i = 0; i < 4; ++i) {
                af[i]  = *(const bf16x8*)(As[h] + (wr * 64 + i * 16 + l15) * 32 + lq * 8);
                bfr[i] = *(const bf16x8*)(Bs[h] + (wc * 64 + i * 16 + l15) * 32 + lq * 8);
            }
            #pragma unroll
            for (int mr = 0; mr < 4; ++mr)
                #pragma unroll
                for (int nc = 0; nc < 4; ++nc)
                    acc[mr][nc] = __builtin_amdgcn_mfma_f32_16x16x32_bf16(
                        af[mr], bfr[nc], acc[mr][nc], 0, 0, 0);
        }
        __syncthreads();
    }

    // epilogue: bias + relu; C/D layout col=lane&15, row=(lane>>4)*4+reg
    #pragma unroll
    for (int nc = 0; nc < 4; ++nc) {
        int gc = n0 + wc * 64 + nc * 16 + l15;
        float bv = bias[gc];
        #pragma unroll
        for (int mr = 0; mr < 4; ++mr) {
            #pragma unroll
            for (int reg = 0; reg < 4; ++reg) {
                int gr = m0 + wr * 64 + mr * 16 + lq * 4 + reg;
                if (gr < M) {
                    float v = fmaxf(acc[mr][nc][reg] + bv, 0.f);
                    if (FINAL) ((float*)outv)[(size_t)gr * 256 + gc] = v;
                    else ((unsigned short*)outv)[(size_t)gr * 256 + gc] = f2bf(v);
                }
            }
        }
    }
}

extern "C" void kernel_launch(void* const* d_in, const int* in_sizes, int n_in,
                              void* d_out, int out_size, void* d_ws, size_t ws_size,
                              hipStream_t stream) {
    const float* x = (const float*)d_in[0];
    const float* Wself[3]  = {(const float*)d_in[1], (const float*)d_in[4], (const float*)d_in[7]};
    const float* Wneigh[3] = {(const float*)d_in[2], (const float*)d_in[5], (const float*)d_in[8]};
    const float* bias[3]   = {(const float*)d_in[3], (const float*)d_in[6], (const float*)d_in[9]};
    const int* src[3] = {(const int*)d_in[10], (const int*)d_in[12], (const int*)d_in[14]};
    const int* dst[3] = {(const int*)d_in[11], (const int*)d_in[13], (const int*)d_in[15]};
    int E[3]    = {in_sizes[10], in_sizes[12], in_sizes[14]};
    int E0 = E[0], E01 = E[0] + E[1], Etot = E[0] + E[1] + E[2];

    // workspace
    unsigned short* h1b = (unsigned short*)d_ws;            // 50000*256
    unsigned short* h2b = h1b + (size_t)50000 * D;          // 12000*256
    unsigned short* meanb = h2b + (size_t)12000 * D;        // 50000*256
    unsigned short* wt  = meanb + (size_t)50000 * D;        // 6*65536 [col][k]
    int* cur            = (int*)(wt + 6 * 65536);           // CURTOT
    unsigned int* flag  = (unsigned int*)(cur + CURTOT);    // NBLK (pad 80)
    int* idxa           = (int*)(flag + 80);                // Etot (<=660000)

    hipMemsetAsync(cur, 0, (CURTOT + 80) * sizeof(int), stream);

    WtArgs wa;
    wa.w[0] = Wself[0]; wa.w[1] = Wneigh[0];
    wa.w[2] = Wself[1]; wa.w[3] = Wneigh[1];
    wa.w[4] = Wself[2]; wa.w[5] = Wneigh[2];
    wa.wt = wt;
    transpose_w<<<96, 256, 0, stream>>>(wa);

    count_all<<<(Etot + 255) / 256, 256, 0, stream>>>(dst[0], dst[1], dst[2],
        cur, E0, E01, Etot);
    scan_lookback<<<NBLK, 256, 0, stream>>>(cur, flag);
    fill_all<<<(Etot + 255) / 256, 256, 0, stream>>>(src[0], src[1], src[2],
        dst[0], dst[1], dst[2], cur, idxa, E0, E01, Etot);

    // layer 0
    gather_mean_k<0><<<(50000 * 64 + 255) / 256, 256, 0, stream>>>(
        x, idxa + 0, cur + SEG0, meanb, 50000);
    sage_gemm_db<0, 1><<<dim3((50000 + 127) / 128, 2), 256, 0, stream>>>(
        x, meanb, wt + 0 * 65536, wt + 1 * 65536, bias[0], h1b, 50000);

    // layer 1
    gather_mean_k<1><<<(12000 * 64 + 255) / 256, 256, 0, stream>>>(
        h1b, idxa + E0, cur + SEG1, meanb, 12000);
    sage_gemm_db<0, 0><<<dim3((12000 + 127) / 128, 2), 256, 0, stream>>>(
        h1b, meanb, wt + 2 * 65536, wt + 3 * 65536, bias[1], h2b, 12000);

    // layer 2
    gather_mean_k<1><<<(4000 * 64 + 255) / 256, 256, 0, stream>>>(
        h2b, idxa + E01, cur + SEG2, meanb, 4000);
    sage_gemm_db<1, 0><<<dim3((4000 + 127) / 128, 2), 256, 0, stream>>>(
        h2b, meanb, wt + 4 * 65536, wt + 5 * 65536, bias[2], d_out, 4000);
}

// Round 15
// 286.698 us; speedup vs baseline: 1.2444x; 1.0598x over previous
//
#include <hip/hip_runtime.h>
#include <stdint.h>

#define D 256

typedef __attribute__((ext_vector_type(8))) short bf16x8;
typedef __attribute__((ext_vector_type(4))) float f32x4;

__device__ inline unsigned short f2bf(float f) {
    union { float f; uint32_t u; } v; v.f = f;
    return (unsigned short)((v.u + 0x7FFFu + ((v.u >> 16) & 1u)) >> 16);
}
__device__ inline float bf2f(unsigned short b) {
    return __uint_as_float(((uint32_t)b) << 16);
}

// segment geometry (padded to 1024-multiples for the block scan)
#define SEG0 0
#define SEG1 50176
#define SEG2 62464
#define CURTOT 66560          // 50176+12288+4096
#define NBLK 65               // seg0 blocks 0-48, seg1 49-60, seg2 61-64

#define TBLK 96               // 6 matrices x 16 tiles of 64x64

// ---------- pre: LDS-tiled weight transpose -> PERMUTED bf16 wt + edge count
// Permuted layout per W (65536 shorts): tile (nb,kt) = 4096 shorts.
// chunk c: g=c>>6, q=(c>>4)&3, cl=c&15 -> col = nb*128+g*16+cl, k = kt*32+q*8+j.
// GEMM Bs staging is linear; bfr ds_reads are canonical.
struct PreArgs {
    const float* w[6];
    unsigned short* wt;
    const int* d0; const int* d1; const int* d2;
    int* cur;
    int E0, E01, Etot;
};

__global__ __launch_bounds__(256) void fused_pre(PreArgs a)
{
    __shared__ float tile[64][65];
    int b = blockIdx.x;
    if (b < TBLK) {
        int m = b >> 4;
        int t16 = b & 15;
        int r0 = (t16 >> 2) * 64, c0 = (t16 & 3) * 64;   // r0 = k base, c0 = col base
        int ty = threadIdx.x >> 4, tx = threadIdx.x & 15;
        const float* w = a.w[m];
        #pragma unroll
        for (int i = 0; i < 4; ++i) {
            int krow = ty * 4 + i;
            float4 v = *(const float4*)(w + (size_t)(r0 + krow) * 256 + c0 + tx * 4);
            tile[krow][tx * 4 + 0] = v.x;
            tile[krow][tx * 4 + 1] = v.y;
            tile[krow][tx * 4 + 2] = v.z;
            tile[krow][tx * 4 + 3] = v.w;
        }
        __syncthreads();
        unsigned short* o = a.wt + (size_t)m * 65536;
        #pragma unroll
        for (int i = 0; i < 4; ++i) {
            int colw = ty * 4 + i;               // col within tile
            int C = c0 + colw;                   // global col
            int K = r0 + tx * 4;                 // global k (aligned 4)
            ushort4 u;
            u.x = f2bf(tile[tx * 4 + 0][colw]);
            u.y = f2bf(tile[tx * 4 + 1][colw]);
            u.z = f2bf(tile[tx * 4 + 2][colw]);
            u.w = f2bf(tile[tx * 4 + 3][colw]);
            int nb = C >> 7, kt = K >> 5;
            int g = (C & 127) >> 4, cl = C & 15;
            int q = (K & 31) >> 3, j = K & 7;
            int c = g * 64 + q * 16 + cl;
            *(ushort4*)(o + (size_t)(nb * 8 + kt) * 4096 + c * 8 + j) = u;
        }
    } else {
        int e = (b - TBLK) * 256 + threadIdx.x;
        if (e >= a.Etot) return;
        int base, d;
        if (e < a.E0)       { base = SEG0; d = a.d0[e]; }
        else if (e < a.E01) { base = SEG1; d = a.d1[e - a.E0]; }
        else                { base = SEG2; d = a.d2[e - a.E01]; }
        atomicAdd(&a.cur[base + d], 1);
    }
}

// ---------- single-pass segmented scan with decoupled lookback ---------------
__global__ __launch_bounds__(256) void scan_lookback(
    int* __restrict__ cur, unsigned int* __restrict__ flag)
{
    __shared__ int wsum[4];
    __shared__ int sprefix;
    int tid = threadIdx.x, lane = tid & 63, wid = tid >> 6;
    int b = blockIdx.x;
    int base = b * 1024 + tid * 4;
    int4 v = *(int4*)(cur + base);
    int t0 = v.x, t01 = t0 + v.y, t012 = t01 + v.z, tot = t012 + v.w;
    int incl = tot;
    #pragma unroll
    for (int ofs = 1; ofs < 64; ofs <<= 1) {
        int t = __shfl_up(incl, ofs, 64);
        if (lane >= ofs) incl += t;
    }
    if (lane == 63) wsum[wid] = incl;
    __syncthreads();
    if (tid == 0) {
        int run = 0;
        #pragma unroll
        for (int w = 0; w < 4; ++w) { int t = wsum[w]; wsum[w] = run; run += t; }
        int segfirst = (b >= 61) ? 61 : (b >= 49) ? 49 : 0;
        int pfx = 0;
        if (b != segfirst) {
            unsigned int f;
            do {
                f = __hip_atomic_load(&flag[b - 1], __ATOMIC_ACQUIRE,
                                      __HIP_MEMORY_SCOPE_AGENT);
            } while (f == 0);
            pfx = (int)(f - 1u);
        }
        __hip_atomic_store(&flag[b], (unsigned int)(pfx + run) + 1u,
                           __ATOMIC_RELEASE, __HIP_MEMORY_SCOPE_AGENT);
        sprefix = pfx;
    }
    __syncthreads();
    int add = sprefix + wsum[wid] + incl - tot;
    v.x = add; v.y = add + t0; v.z = add + t01; v.w = add + t012;
    *(int4*)(cur + base) = v;
}

// fill: idx[cursor(dst)] = src; afterwards cur[] holds INCLUSIVE offsets
__global__ __launch_bounds__(256) void fill_all(
    const int* __restrict__ s0, const int* __restrict__ s1, const int* __restrict__ s2,
    const int* __restrict__ d0, const int* __restrict__ d1, const int* __restrict__ d2,
    int* __restrict__ cur, int* __restrict__ idx, int E0, int E01, int Etot)
{
    int e = blockIdx.x * 256 + threadIdx.x;
    if (e >= Etot) return;
    int base, d, s, ib;
    if (e < E0)       { base = SEG0; d = d0[e];       s = s0[e];       ib = 0; }
    else if (e < E01) { base = SEG1; d = d1[e - E0];  s = s1[e - E0];  ib = E0; }
    else              { base = SEG2; d = d2[e - E01]; s = s2[e - E01]; ib = E01; }
    int p = atomicAdd(&cur[base + d], 1);
    idx[ib + p] = s;
}

// ---------- gather + mean (one wave per dst row), 4-deep unroll --------------
template<int BF16IN>
__global__ __launch_bounds__(256) void gather_mean_k(
    const void* __restrict__ hv, const int* __restrict__ idx,
    const int* __restrict__ curseg, unsigned short* __restrict__ mean, int M)
{
    int t = blockIdx.x * blockDim.x + threadIdx.x;
    int w = t >> 6, lane = t & 63;
    if (w >= M) return;
    int e0 = w ? curseg[w - 1] : 0;
    int e1 = curseg[w];
    float4 acc0 = make_float4(0.f, 0.f, 0.f, 0.f);
    float4 acc1 = make_float4(0.f, 0.f, 0.f, 0.f);
    int e = e0;
    if (BF16IN) {
        const unsigned short* h = (const unsigned short*)hv;
        for (; e + 3 < e1; e += 4) {
            int sa = idx[e], sb = idx[e + 1], sc = idx[e + 2], sd = idx[e + 3];
            ushort4 va = *(const ushort4*)(h + (size_t)sa * D + lane * 4);
            ushort4 vb = *(const ushort4*)(h + (size_t)sb * D + lane * 4);
            ushort4 vc = *(const ushort4*)(h + (size_t)sc * D + lane * 4);
            ushort4 vd = *(const ushort4*)(h + (size_t)sd * D + lane * 4);
            acc0.x += bf2f(va.x) + bf2f(vb.x);
            acc0.y += bf2f(va.y) + bf2f(vb.y);
            acc0.z += bf2f(va.z) + bf2f(vb.z);
            acc0.w += bf2f(va.w) + bf2f(vb.w);
            acc1.x += bf2f(vc.x) + bf2f(vd.x);
            acc1.y += bf2f(vc.y) + bf2f(vd.y);
            acc1.z += bf2f(vc.z) + bf2f(vd.z);
            acc1.w += bf2f(vc.w) + bf2f(vd.w);
        }
        for (; e < e1; ++e) {
            int sa = idx[e];
            ushort4 va = *(const ushort4*)(h + (size_t)sa * D + lane * 4);
            acc0.x += bf2f(va.x); acc0.y += bf2f(va.y);
            acc0.z += bf2f(va.z); acc0.w += bf2f(va.w);
        }
    } else {
        const float* h = (const float*)hv;
        for (; e + 3 < e1; e += 4) {
            int sa = idx[e], sb = idx[e + 1], sc = idx[e + 2], sd = idx[e + 3];
            float4 va = *((const float4*)(h + (size_t)sa * D) + lane);
            float4 vb = *((const float4*)(h + (size_t)sb * D) + lane);
            float4 vc = *((const float4*)(h + (size_t)sc * D) + lane);
            float4 vd = *((const float4*)(h + (size_t)sd * D) + lane);
            acc0.x += va.x + vb.x; acc0.y += va.y + vb.y;
            acc0.z += va.z + vb.z; acc0.w += va.w + vb.w;
            acc1.x += vc.x + vd.x; acc1.y += vc.y + vd.y;
            acc1.z += vc.z + vd.z; acc1.w += vc.w + vd.w;
        }
        for (; e < e1; ++e) {
            int sa = idx[e];
            float4 va = *((const float4*)(h + (size_t)sa * D) + lane);
            acc0.x += va.x; acc0.y += va.y; acc0.z += va.z; acc0.w += va.w;
        }
    }
    acc0.x += acc1.x; acc0.y += acc1.y; acc0.z += acc1.z; acc0.w += acc1.w;
    float r = 1.0f / fmaxf((float)(e1 - e0), 1.0f);
    ushort4 o;
    o.x = f2bf(acc0.x * r); o.y = f2bf(acc0.y * r);
    o.z = f2bf(acc0.z * r); o.w = f2bf(acc0.w * r);
    *(ushort4*)(mean + (size_t)w * D + lane * 4) = o;
}

// ---------- MFMA GEMM (R12-proven structure + LDS-repack epilogue) ----------
// out = relu(A1@W1 + A2@W2 + b). 128x128 tile, 4 waves (2x2) of 64x64,
// K=512 as 16 steps of 32. B (wt) pre-permuted: staging linear, reads canonical.
template<int FINAL, int A1F32>
__global__ __launch_bounds__(256) void sage_gemm_mfma(
    const void* __restrict__ A1v,
    const unsigned short* __restrict__ A2,
    const unsigned short* __restrict__ Wt1,
    const unsigned short* __restrict__ Wt2,
    const float* __restrict__ bias,
    void* __restrict__ outv,
    int M)
{
    __shared__ unsigned short lds_u[8192];    // As = [0,4096), Bs = [4096,8192)
    unsigned short* As = lds_u;
    unsigned short* Bs = lds_u + 4096;

    int tid = threadIdx.x;
    int lane = tid & 63, wid = tid >> 6;
    int wr = wid >> 1, wc = wid & 1;
    int m0 = blockIdx.x * 128, n0 = blockIdx.y * 128;
    int nb = blockIdx.y;
    int l15 = lane & 15, lq = lane >> 4;

    f32x4 acc[4][4] = {};

    for (int kt = 0; kt < 16; ++kt) {
        int kk = (kt & 7) * 32;
        // ---- A tile 128x32 bf16 (8 KB) ----
        if (A1F32 && kt < 8) {
            const float* A = (const float*)A1v;
            #pragma unroll
            for (int q = 0; q < 2; ++q) {
                int ch = q * 256 + tid;
                int r = ch >> 2, c16 = ch & 3;
                int gr = m0 + r; if (gr >= M) gr = M - 1;
                const float* s = A + (size_t)gr * 256 + kk + c16 * 8;
                float4 u0 = *(const float4*)s;
                float4 u1 = *(const float4*)(s + 4);
                unsigned short rr[8] = {f2bf(u0.x), f2bf(u0.y), f2bf(u0.z), f2bf(u0.w),
                                        f2bf(u1.x), f2bf(u1.y), f2bf(u1.z), f2bf(u1.w)};
                *(uint4*)(As + ch * 8) = *(uint4*)rr;
            }
        } else {
            const unsigned short* A = (kt < 8) ? (const unsigned short*)A1v : A2;
            #pragma unroll
            for (int q = 0; q < 2; ++q) {
                int ch = q * 256 + tid;
                int r = ch >> 2, c16 = ch & 3;
                int gr = m0 + r; if (gr >= M) gr = M - 1;
                const unsigned short* s = A + (size_t)gr * 256 + kk + c16 * 8;
                __builtin_amdgcn_global_load_lds(
                    (const __attribute__((address_space(1))) void*)s,
                    (__attribute__((address_space(3))) void*)(As + (q * 256 + wid * 64) * 8),
                    16, 0, 0);
            }
        }
        // ---- B tile (8 KB): LINEAR staging from pre-permuted wt ----
        {
            const unsigned short* B = (kt < 8) ? Wt1 : Wt2;
            const unsigned short* tb = B + (size_t)(nb * 8 + (kt & 7)) * 4096;
            #pragma unroll
            for (int q = 0; q < 2; ++q) {
                int ch = q * 256 + tid;
                const unsigned short* s = tb + ch * 8;
                __builtin_amdgcn_global_load_lds(
                    (const __attribute__((address_space(1))) void*)s,
                    (__attribute__((address_space(3))) void*)(Bs + (q * 256 + wid * 64) * 8),
                    16, 0, 0);
            }
        }
        __syncthreads();

        bf16x8 af[4], bfr[4];
        #pragma unroll
        for (int i = 0; i < 4; ++i) {
            af[i]  = *(const bf16x8*)(As + (wr * 64 + i * 16 + l15) * 32 + lq * 8);
            bfr[i] = *(const bf16x8*)(Bs + ((wc * 4 + i) * 64 + lq * 16 + l15) * 8);
        }
        #pragma unroll
        for (int mr = 0; mr < 4; ++mr)
            #pragma unroll
            for (int nc = 0; nc < 4; ++nc)
                acc[mr][nc] = __builtin_amdgcn_mfma_f32_16x16x32_bf16(
                    af[mr], bfr[nc], acc[mr][nc], 0, 0, 0);
        __syncthreads();
    }

    // epilogue: bias + relu; C/D layout col=lane&15, row=(lane>>4)*4+reg
    float bv[4];
    #pragma unroll
    for (int nc = 0; nc < 4; ++nc) bv[nc] = bias[n0 + wc * 64 + nc * 16 + l15];

    if (FINAL) {
        // fp32 output, full precision, scalar stores (small layer)
        #pragma unroll
        for (int nc = 0; nc < 4; ++nc) {
            int gc = n0 + wc * 64 + nc * 16 + l15;
            #pragma unroll
            for (int mr = 0; mr < 4; ++mr)
                #pragma unroll
                for (int reg = 0; reg < 4; ++reg) {
                    int gr = m0 + wr * 64 + mr * 16 + lq * 4 + reg;
                    if (gr < M)
                        ((float*)outv)[(size_t)gr * 256 + gc] =
                            fmaxf(acc[mr][nc][reg] + bv[nc], 0.f);
                }
        }
    } else {
        // bf16 output: repack each wave's 64x64 tile via LDS in two 32-row
        // halves (wave arena = 4KB) -> 16B fully-coalesced global stores.
        unsigned short* outp = (unsigned short*)outv;
        #pragma unroll
        for (int half = 0; half < 2; ++half) {
            __syncthreads();
            #pragma unroll
            for (int mr2 = 0; mr2 < 2; ++mr2) {
                int mr = half * 2 + mr2;
                #pragma unroll
                for (int nc = 0; nc < 4; ++nc)
                    #pragma unroll
                    for (int reg = 0; reg < 4; ++reg) {
                        int lr = mr2 * 16 + lq * 4 + reg;
                        lds_u[wid * 2048 + lr * 64 + nc * 16 + l15] =
                            f2bf(fmaxf(acc[mr][nc][reg] + bv[nc], 0.f));
                    }
            }
            __syncthreads();
            #pragma unroll
            for (int i = 0; i < 4; ++i) {
                int lr = i * 8 + (lane >> 3);
                int grow = m0 + wr * 64 + half * 32 + lr;
                if (grow < M) {
                    uint4 u = *(uint4*)(lds_u + wid * 2048 + lr * 64 + (lane & 7) * 8);
                    *(uint4*)(outp + (size_t)grow * 256 + n0 + wc * 64 + (lane & 7) * 8) = u;
                }
            }
        }
    }
}

extern "C" void kernel_launch(void* const* d_in, const int* in_sizes, int n_in,
                              void* d_out, int out_size, void* d_ws, size_t ws_size,
                              hipStream_t stream) {
    const float* x = (const float*)d_in[0];
    const float* Wself[3]  = {(const float*)d_in[1], (const float*)d_in[4], (const float*)d_in[7]};
    const float* Wneigh[3] = {(const float*)d_in[2], (const float*)d_in[5], (const float*)d_in[8]};
    const float* bias[3]   = {(const float*)d_in[3], (const float*)d_in[6], (const float*)d_in[9]};
    const int* src[3] = {(const int*)d_in[10], (const int*)d_in[12], (const int*)d_in[14]};
    const int* dst[3] = {(const int*)d_in[11], (const int*)d_in[13], (const int*)d_in[15]};
    int E[3]    = {in_sizes[10], in_sizes[12], in_sizes[14]};
    int E0 = E[0], E01 = E[0] + E[1], Etot = E[0] + E[1] + E[2];

    // workspace
    unsigned short* h1b = (unsigned short*)d_ws;            // 50000*256
    unsigned short* h2b = h1b + (size_t)50000 * D;          // 12000*256
    unsigned short* meanb = h2b + (size_t)12000 * D;        // 50000*256
    unsigned short* wt  = meanb + (size_t)50000 * D;        // 6*65536 permuted
    int* cur            = (int*)(wt + 6 * 65536);           // CURTOT
    unsigned int* flag  = (unsigned int*)(cur + CURTOT);    // NBLK (pad 80)
    int* idxa           = (int*)(flag + 80);                // Etot (<=660000)

    hipMemsetAsync(cur, 0, (CURTOT + 80) * sizeof(int), stream);

    PreArgs pa;
    pa.w[0] = Wself[0]; pa.w[1] = Wneigh[0];
    pa.w[2] = Wself[1]; pa.w[3] = Wneigh[1];
    pa.w[4] = Wself[2]; pa.w[5] = Wneigh[2];
    pa.wt = wt;
    pa.d0 = dst[0]; pa.d1 = dst[1]; pa.d2 = dst[2];
    pa.cur = cur; pa.E0 = E0; pa.E01 = E01; pa.Etot = Etot;
    int cblk = (Etot + 255) / 256;
    fused_pre<<<TBLK + cblk, 256, 0, stream>>>(pa);

    scan_lookback<<<NBLK, 256, 0, stream>>>(cur, flag);

    fill_all<<<(Etot + 255) / 256, 256, 0, stream>>>(src[0], src[1], src[2],
        dst[0], dst[1], dst[2], cur, idxa, E0, E01, Etot);

    // layer 0
    gather_mean_k<0><<<(50000 * 64 + 255) / 256, 256, 0, stream>>>(
        x, idxa + 0, cur + SEG0, meanb, 50000);
    sage_gemm_mfma<0, 1><<<dim3((50000 + 127) / 128, 2), 256, 0, stream>>>(
        x, meanb, wt + 0 * 65536, wt + 1 * 65536, bias[0], h1b, 50000);

    // layer 1
    gather_mean_k<1><<<(12000 * 64 + 255) / 256, 256, 0, stream>>>(
        h1b, idxa + E0, cur + SEG1, meanb, 12000);
    sage_gemm_mfma<0, 0><<<dim3((12000 + 127) / 128, 2), 256, 0, stream>>>(
        h1b, meanb, wt + 2 * 65536, wt + 3 * 65536, bias[1], h2b, 12000);

    // layer 2
    gather_mean_k<1><<<(4000 * 64 + 255) / 256, 256, 0, stream>>>(
        h2b, idxa + E01, cur + SEG2, meanb, 4000);
    sage_gemm_mfma<1, 0><<<dim3((4000 + 127) / 128, 2), 256, 0, stream>>>(
        h2b, meanb, wt + 4 * 65536, wt + 5 * 65536, bias[2], d_out, 4000);
}